// Round 3
// baseline (203.690 us; speedup 1.0000x reference)
//
#include <hip/hip_runtime.h>
#include <hip/hip_bf16.h>

#define NN 64
#define CC 3
#define LL 4096
#define KK 128
#define SS 64
#define WW 4033           // LL - SS + 1
#define TILES 32          // 32 tiles of 128 windows per n

typedef __attribute__((ext_vector_type(8))) short v8s;   // 8 bf16 (4 VGPR) MFMA A/B frag
typedef __attribute__((ext_vector_type(4))) float v4f;   // 4 fp32 MFMA C/D frag

// ---- ws layout (bytes) ----
// d2g:  u32[NN*KK]        @ 0       (32768)
// cnt:  u32[NN]           @ 32768   (256)   per-n completed-block counters
// hs2g: f32[CC*KK]        @ 33024   (1536)  -0.5*||s||^2
// shb:  uint4[CC*1024]    @ 34560   (49152) fragment-order bf16 shapelets
#define WS_CNT_OFF 32768
#define WS_HS2_OFF 33024
#define WS_SHB_OFF 34560

__device__ __forceinline__ unsigned bf16_rne(float f) {
    unsigned u = __float_as_uint(f);
    return (u + 0x7FFFu + ((u >> 16) & 1u)) >> 16;
}

// ---------------------------------------------------------------------------
// Prep (single launch): init d2g=+inf, cnt=0, hs2, frag-order bf16 pack.
// Grid: 32 blocks x 256.
__global__ void me_prep(const float* __restrict__ shp,
                        unsigned* __restrict__ d2g,
                        unsigned* __restrict__ cnt,
                        float* __restrict__ hs2g,
                        uint4* __restrict__ shb) {
    int tid = blockIdx.x * 256 + threadIdx.x;
    if (tid < NN * KK) d2g[tid] = 0x7F800000u;     // +inf bits
    if (tid < NN) cnt[tid] = 0u;
    if (tid < CC * KK) {
        const float* r = shp + tid * SS;
        float a = 0.f;
        #pragma unroll 8
        for (int s = 0; s < SS; ++s) a += r[s] * r[s];
        hs2g[tid] = -0.5f * a;
    }
    if (tid < CC * 1024) {
        // chunk = ((c*8 + mt)*2 + sc)*64 + lane:
        //   shp[c][mt*16 + (lane&15)][sc*32 + (lane>>4)*8 + j], j=0..7 (RNE bf16)
        int c  = tid >> 10;
        int r  = tid & 1023;
        int mt = r >> 7;
        int sc = (r >> 6) & 1;
        int l  = r & 63;
        int row  = mt * 16 + (l & 15);
        int koff = sc * 32 + (l >> 4) * 8;
        const float* s = shp + ((size_t)(c * KK + row)) * SS + koff;
        float4 f0 = *(const float4*)s;
        float4 f1 = *(const float4*)(s + 4);
        uint4 o;
        o.x = (bf16_rne(f0.y) << 16) | bf16_rne(f0.x);
        o.y = (bf16_rne(f0.w) << 16) | bf16_rne(f0.z);
        o.z = (bf16_rne(f1.y) << 16) | bf16_rne(f1.x);
        o.w = (bf16_rne(f1.w) << 16) | bf16_rne(f1.z);
        shb[tid] = o;
    }
}

// ---------------------------------------------------------------------------
// Main: one block per (n, 128-window tile); 4 waves; wave = 32 windows x 128 k.
// All 3 channels staged ONCE (48 KB frag-order shapelets via global_load_lds),
// prefix scans read global directly so the first barrier is also the DMA drain.
// acc init = -0.5*x2[w]; epi adds -0.5*s2[k]; min d2 = max(-2*maxD, 0).
// Last block per n (atomic counter) writes sqrt to d_out — no separate kernels.
__global__ __launch_bounds__(256, 2) void me_main(
        const float* __restrict__ x,
        const ushort* __restrict__ shb_g,
        const float* __restrict__ hs2g,
        unsigned* __restrict__ d2g,
        unsigned* __restrict__ cnt,
        float* __restrict__ out) {

    __shared__ __align__(16) ushort shb[CC * 8192];  // 49152 B frag-order A tiles
    __shared__ __align__(16) float xs[CC][192];      // x tiles fp32
    __shared__ float ps[CC][192];                    // prefix of squares
    __shared__ float hx2s[CC][128];                  // -0.5*x2 (or -1e30 invalid)
    __shared__ __align__(16) float hs2s[CC][128];    // -0.5*s2, all channels
    __shared__ unsigned red[KK];
    __shared__ int lastflag;

    const int b    = blockIdx.x;
    const int n    = b >> 5;
    const int tile = b & 31;
    const int w0   = tile * 128;
    const int t    = threadIdx.x;
    const int lane = t & 63, wave = t >> 6;
    const int quad = lane >> 4, col = lane & 15;
    const int wbase = wave * 32;

    if (t < KK) red[t] = 0x7F800000u;

    // ---- issue DMA: all 3072 shapelet chunks, global(ws) -> LDS ----
    {
        typedef __attribute__((address_space(1))) const uint4 gu4;
        typedef __attribute__((address_space(3))) uint4 lu4;
        const uint4* gbase = (const uint4*)shb_g;
        #pragma unroll
        for (int it = 0; it < 12; ++it) {
            const uint4* gp = gbase + it * 256 + t;                 // per-lane
            uint4* lp = (uint4*)shb + (it * 256 + wave * 64);       // wave-uniform
            __builtin_amdgcn_global_load_lds((gu4*)gp, (lu4*)lp, 16, 0, 0);
        }
    }

    const float* xb = x + (size_t)n * (CC * LL);

    // ---- stage x tiles: 3 x 48 float4, zero-fill past L ----
    if (t < 144) {
        int ch = t / 48, q = t - ch * 48;
        int i = q * 4, gi = w0 + i;
        float4 v;
        if (gi + 3 < LL) v = *(const float4*)(xb + ch * LL + gi);
        else {
            v.x = (gi     < LL) ? xb[ch * LL + gi]     : 0.f;
            v.y = (gi + 1 < LL) ? xb[ch * LL + gi + 1] : 0.f;
            v.z = (gi + 2 < LL) ? xb[ch * LL + gi + 2] : 0.f;
            v.w = 0.f;
        }
        *(float4*)(&xs[ch][i]) = v;
    }
    // ---- stage -0.5*s2, all channels ----
    if (t < 96) *(float4*)(&hs2s[0][0] + t * 4) = *(const float4*)(hs2g + t * 4);

    // ---- prefix scan of squares, one wave per channel, GLOBAL reads ----
    // (runs before the first barrier so it overlaps the shapelet DMA)
    if (wave < 3) {
        const float* xc = xb + wave * LL;
        float carry = 0.f;
        for (int seg = 0; seg < 3; ++seg) {
            int gi = w0 + seg * 64 + lane;
            float v = (gi < LL) ? xc[gi] : 0.f;
            v = v * v;
            #pragma unroll
            for (int d = 1; d < 64; d <<= 1) {
                float u = __shfl_up(v, d, 64);
                if (lane >= d) v += u;
            }
            v += carry;
            ps[wave][seg * 64 + lane] = v;
            carry = __shfl(v, 63, 64);
        }
    }
    __syncthreads();   // drains DMA (vmcnt) + all LDS stages

    if (t < 128) {
        #pragma unroll
        for (int c = 0; c < CC; ++c) {
            float I1 = ps[c][t + 63];
            float I0 = (t > 0) ? ps[c][t - 1] : 0.f;
            hx2s[c][t] = (w0 + t < WW) ? (-0.5f * (I1 - I0)) : -1e30f;
        }
    }
    __syncthreads();

    // ---- MFMA phase: 3 channels x 2 k-chunks x 8 m-tiles x 2 n-tiles ----
    float hx0[CC], hx1[CC];
    #pragma unroll
    for (int c = 0; c < CC; ++c) {
        hx0[c] = hx2s[c][wbase + col];
        hx1[c] = hx2s[c][wbase + 16 + col];
    }

    float rmax[8][4];
    #pragma unroll
    for (int m = 0; m < 8; ++m)
        #pragma unroll
        for (int r = 0; r < 4; ++r) rmax[m][r] = -3.4e38f;

    #pragma unroll
    for (int c = 0; c < CC; ++c) {
        v4f acc[8][2];
        #pragma unroll
        for (int m = 0; m < 8; ++m) {
            v4f a0 = {hx0[c], hx0[c], hx0[c], hx0[c]};
            v4f a1 = {hx1[c], hx1[c], hx1[c], hx1[c]};
            acc[m][0] = a0; acc[m][1] = a1;
        }
        #pragma unroll
        for (int sc = 0; sc < 2; ++sc) {
            v8s bf[2];
            #pragma unroll
            for (int nt = 0; nt < 2; ++nt) {
                const float* xp = &xs[c][0] + (wbase + nt * 16 + col + sc * 32 + quad * 8);
                float f0 = xp[0], f1 = xp[1], f2 = xp[2], f3 = xp[3];
                float f4 = xp[4], f5 = xp[5], f6 = xp[6], f7 = xp[7];
                union { v8s v; unsigned u[4]; } bu;
                bu.u[0] = __builtin_amdgcn_perm(__float_as_uint(f1), __float_as_uint(f0), 0x07060302u);
                bu.u[1] = __builtin_amdgcn_perm(__float_as_uint(f3), __float_as_uint(f2), 0x07060302u);
                bu.u[2] = __builtin_amdgcn_perm(__float_as_uint(f5), __float_as_uint(f4), 0x07060302u);
                bu.u[3] = __builtin_amdgcn_perm(__float_as_uint(f7), __float_as_uint(f6), 0x07060302u);
                bf[nt] = bu.v;
            }
            #pragma unroll
            for (int m = 0; m < 8; ++m) {
                v8s af = *(const v8s*)(shb + ((c * 16 + m * 2 + sc) * 64 + lane) * 8);
                acc[m][0] = __builtin_amdgcn_mfma_f32_16x16x32_bf16(af, bf[0], acc[m][0], 0, 0, 0);
                acc[m][1] = __builtin_amdgcn_mfma_f32_16x16x32_bf16(af, bf[1], acc[m][1], 0, 0, 0);
            }
        }
        #pragma unroll
        for (int m = 0; m < 8; ++m) {
            v4f h = *(const v4f*)(&hs2s[c][m * 16 + quad * 4]);
            #pragma unroll
            for (int r = 0; r < 4; ++r)
                rmax[m][r] = fmaxf(rmax[m][r],
                                   fmaxf(acc[m][0][r], acc[m][1][r]) + h[r]);
        }
    }

    // ---- reduce over 16 window-columns; block LDS reduce; global atomicMin ----
    #pragma unroll
    for (int m = 0; m < 8; ++m) {
        #pragma unroll
        for (int r = 0; r < 4; ++r) {
            float v = rmax[m][r];
            v = fmaxf(v, __shfl_xor(v, 1, 64));
            v = fmaxf(v, __shfl_xor(v, 2, 64));
            v = fmaxf(v, __shfl_xor(v, 4, 64));
            v = fmaxf(v, __shfl_xor(v, 8, 64));
            rmax[m][r] = v;
        }
    }
    if (col == 0) {
        #pragma unroll
        for (int m = 0; m < 8; ++m)
            #pragma unroll
            for (int r = 0; r < 4; ++r) {
                int k = m * 16 + quad * 4 + r;
                float d2 = fmaxf(-2.f * rmax[m][r], 0.f);
                atomicMin(&red[k], __float_as_uint(d2));
            }
    }
    __syncthreads();
    if (t < KK) atomicMin(&d2g[n * KK + t], red[t]);   // device-scope

    // ---- last block for this n writes sqrt -> out ----
    __threadfence();
    __syncthreads();
    if (t == 0) {
        unsigned old = atomicAdd(&cnt[n], 1u);
        lastflag = (old == TILES - 1) ? 1 : 0;
    }
    __syncthreads();
    if (lastflag && t < KK) {
        // no-op atomic = coherent device-scope read of the final min
        unsigned bits = atomicMin(&d2g[n * KK + t], 0x7F800000u);
        out[n * KK + t] = sqrtf(__uint_as_float(bits));
    }
}

// ---------------------------------------------------------------------------
extern "C" void kernel_launch(void* const* d_in, const int* in_sizes, int n_in,
                              void* d_out, int out_size, void* d_ws, size_t ws_size,
                              hipStream_t stream) {
    const float* x   = (const float*)d_in[0];   // (N, C, L) fp32
    const float* shp = (const float*)d_in[1];   // (C, K, S) fp32
    unsigned* d2g  = (unsigned*)d_ws;
    unsigned* cnt  = (unsigned*)((char*)d_ws + WS_CNT_OFF);
    float*    hs2g = (float*)((char*)d_ws + WS_HS2_OFF);
    uint4*    shb  = (uint4*)((char*)d_ws + WS_SHB_OFF);
    float* out = (float*)d_out;

    hipLaunchKernelGGL(me_prep, dim3(32), dim3(256), 0, stream, shp, d2g, cnt, hs2g, shb);
    hipLaunchKernelGGL(me_main, dim3(NN * TILES), dim3(256), 0, stream,
                       x, (const ushort*)shb, hs2g, d2g, cnt, out);
}

// Round 4
// 106.601 us; speedup vs baseline: 1.9108x; 1.9108x over previous
//
#include <hip/hip_runtime.h>
#include <hip/hip_bf16.h>

#define NN 64
#define CC 3
#define LL 4096
#define SS 64
#define KK 128
#define WW 4033           // LL - SS + 1
#define TILES 32          // 32 tiles of 128 windows per n

typedef __attribute__((ext_vector_type(8))) short v8s;   // 8 bf16 (4 VGPR) MFMA A/B frag
typedef __attribute__((ext_vector_type(4))) float v4f;   // 4 fp32 MFMA C/D frag

// ---- ws layout (bytes) ----
// d2g:  u32[NN*KK]        @ 0       (32768)
// cnt:  u32[NN]           @ 32768   (256)
// hs2g: f32[CC*KK]        @ 33024   (1536)  -0.5*||s||^2
// shb:  uint4[CC*1024]    @ 34560   (49152) fragment-order bf16 shapelets
#define WS_CNT_OFF 32768
#define WS_HS2_OFF 33024
#define WS_SHB_OFF 34560

__device__ __forceinline__ unsigned bf16_rne(float f) {
    unsigned u = __float_as_uint(f);
    return (u + 0x7FFFu + ((u >> 16) & 1u)) >> 16;
}

// ---------------------------------------------------------------------------
// Prep (single launch): init d2g=+inf, cnt=0, hs2, frag-order bf16 pack.
__global__ void me_prep(const float* __restrict__ shp,
                        unsigned* __restrict__ d2g,
                        unsigned* __restrict__ cnt,
                        float* __restrict__ hs2g,
                        uint4* __restrict__ shb) {
    int tid = blockIdx.x * 256 + threadIdx.x;
    if (tid < NN * KK) d2g[tid] = 0x7F800000u;     // +inf bits
    if (tid < NN) cnt[tid] = 0u;
    if (tid < CC * KK) {
        const float* r = shp + tid * SS;
        float a = 0.f;
        #pragma unroll 8
        for (int s = 0; s < SS; ++s) a += r[s] * r[s];
        hs2g[tid] = -0.5f * a;
    }
    if (tid < CC * 1024) {
        // chunk = ((c*8 + mt)*2 + sc)*64 + lane:
        //   shp[c][mt*16 + (lane&15)][sc*32 + (lane>>4)*8 + j], j=0..7 (RNE bf16)
        int c  = tid >> 10;
        int r  = tid & 1023;
        int mt = r >> 7;
        int sc = (r >> 6) & 1;
        int l  = r & 63;
        int row  = mt * 16 + (l & 15);
        int koff = sc * 32 + (l >> 4) * 8;
        const float* s = shp + ((size_t)(c * KK + row)) * SS + koff;
        float4 f0 = *(const float4*)s;
        float4 f1 = *(const float4*)(s + 4);
        uint4 o;
        o.x = (bf16_rne(f0.y) << 16) | bf16_rne(f0.x);
        o.y = (bf16_rne(f0.w) << 16) | bf16_rne(f0.z);
        o.z = (bf16_rne(f1.y) << 16) | bf16_rne(f1.x);
        o.w = (bf16_rne(f1.w) << 16) | bf16_rne(f1.z);
        shb[tid] = o;
    }
}

// ---------------------------------------------------------------------------
// Main: one block per (n, 128-window tile); 4 waves; wave = 32 windows x 128 k.
// Single pre-MFMA barrier: shapelet DMA + x stage + register prefix scan all
// overlap, then one __syncthreads (which also drains the DMA vmcnt).
// acc init = -0.5*x2[w]; epi adds -0.5*s2[k]; min d2 = max(-2*maxD, 0).
// NO __threadfence: atomics are device-scope RMWs at the coherence point;
// __syncthreads' vmcnt(0) drain orders d2g mins before the cnt increment.
__global__ __launch_bounds__(256, 3) void me_main(
        const float* __restrict__ x,
        const ushort* __restrict__ shb_g,
        const float* __restrict__ hs2g,
        unsigned* __restrict__ d2g,
        unsigned* __restrict__ cnt,
        float* __restrict__ out) {

    __shared__ __align__(16) ushort shb[CC * 8192];  // 49152 B frag-order A tiles
    __shared__ ushort xs16[CC * 192];                // x tiles, bf16 (1152 B)
    __shared__ float hx2s[CC][128];                  // -0.5*x2 (or -1e30 invalid)
    __shared__ __align__(16) float hs2s[CC * 128];   // -0.5*s2, all channels
    __shared__ unsigned red[KK];
    __shared__ int lastflag;

    const int b    = blockIdx.x;
    const int n    = b >> 5;
    const int tile = b & 31;
    const int w0   = tile * 128;
    const int t    = threadIdx.x;
    const int lane = t & 63, wave = t >> 6;
    const int quad = lane >> 4, col = lane & 15;
    const int wbase = wave * 32;

    if (t < KK) red[t] = 0x7F800000u;

    // ---- issue DMA: all 3072 shapelet chunks, global(ws) -> LDS ----
    {
        typedef __attribute__((address_space(1))) const uint4 gu4;
        typedef __attribute__((address_space(3))) uint4 lu4;
        const uint4* gbase = (const uint4*)shb_g;
        #pragma unroll
        for (int it = 0; it < 12; ++it) {
            const uint4* gp = gbase + it * 256 + t;                 // per-lane
            uint4* lp = (uint4*)shb + (it * 256 + wave * 64);       // wave-uniform
            __builtin_amdgcn_global_load_lds((gu4*)gp, (lu4*)lp, 16, 0, 0);
        }
    }

    const float* xb = x + (size_t)n * (CC * LL);

    // ---- stage -0.5*s2, all channels (384 floats) ----
    if (t < 96) *(float4*)(hs2s + t * 4) = *(const float4*)(hs2g + t * 4);

    // ---- one wave per channel: stage x (bf16) + prefix scan + hx2, no LDS scratch ----
    if (wave < 3) {
        const float* xc = xb + wave * LL;
        float P0, P1, P2;
        {
            float carry = 0.f;
            #pragma unroll
            for (int seg = 0; seg < 3; ++seg) {
                int gi = w0 + seg * 64 + lane;
                float v = (gi < LL) ? xc[gi] : 0.f;
                xs16[wave * 192 + seg * 64 + lane] = (ushort)bf16_rne(v);
                float sq = v * v;
                #pragma unroll
                for (int d = 1; d < 64; d <<= 1) {
                    float u = __shfl_up(sq, d, 64);
                    if (lane >= d) sq += u;
                }
                sq += carry;
                if (seg == 0) P0 = sq; else if (seg == 1) P1 = sq; else P2 = sq;
                carry = __shfl(sq, 63, 64);
            }
        }
        // window w: x2 = P[w+63] - P[w-1]
        float p0u = __shfl_up(P0, 1, 64);     // P[lane-1]
        float p1u = __shfl_up(P1, 1, 64);     // P[lane+63]  (lane>=1)
        float p2u = __shfl_up(P2, 1, 64);     // P[lane+127] (lane>=1)
        float P0e = __shfl(P0, 63, 64);       // P[63]
        float P1e = __shfl(P1, 63, 64);       // P[127]
        float I1a = (lane == 0) ? P0e : p1u;  // P[lane+63]
        float I0a = (lane == 0) ? 0.f : p0u;  // P[lane-1]
        float I1b = (lane == 0) ? P1e : p2u;  // P[lane+127]
        hx2s[wave][lane]      = (w0 + lane < WW)      ? (-0.5f * (I1a - I0a)) : -1e30f;
        hx2s[wave][64 + lane] = (w0 + 64 + lane < WW) ? (-0.5f * (I1b - I1a)) : -1e30f;
    }
    __syncthreads();   // drains DMA (vmcnt) + all LDS stages — the ONLY pre-MFMA barrier

    // ---- MFMA phase: 3 channels x 2 k-chunks x 8 m-tiles x 2 n-tiles ----
    float hx0[CC], hx1[CC];
    #pragma unroll
    for (int c = 0; c < CC; ++c) {
        hx0[c] = hx2s[c][wbase + col];
        hx1[c] = hx2s[c][wbase + 16 + col];
    }

    float rmax[8][4];
    #pragma unroll
    for (int m = 0; m < 8; ++m)
        #pragma unroll
        for (int r = 0; r < 4; ++r) rmax[m][r] = -3.4e38f;

    #pragma unroll
    for (int c = 0; c < CC; ++c) {
        v4f acc[8][2];
        #pragma unroll
        for (int m = 0; m < 8; ++m) {
            v4f a0 = {hx0[c], hx0[c], hx0[c], hx0[c]};
            v4f a1 = {hx1[c], hx1[c], hx1[c], hx1[c]};
            acc[m][0] = a0; acc[m][1] = a1;
        }
        #pragma unroll
        for (int sc = 0; sc < 2; ++sc) {
            v8s bf[2];
            #pragma unroll
            for (int nt = 0; nt < 2; ++nt) {
                const ushort* xp = xs16 + c * 192 + (wbase + nt * 16 + col + sc * 32 + quad * 8);
                union { v8s v; unsigned u[4]; } bu;
                #pragma unroll
                for (int q = 0; q < 4; ++q)
                    bu.u[q] = (unsigned)xp[2 * q] | ((unsigned)xp[2 * q + 1] << 16);
                bf[nt] = bu.v;
            }
            #pragma unroll
            for (int m = 0; m < 8; ++m) {
                v8s af = *(const v8s*)(shb + ((c * 16 + m * 2 + sc) * 64 + lane) * 8);
                acc[m][0] = __builtin_amdgcn_mfma_f32_16x16x32_bf16(af, bf[0], acc[m][0], 0, 0, 0);
                acc[m][1] = __builtin_amdgcn_mfma_f32_16x16x32_bf16(af, bf[1], acc[m][1], 0, 0, 0);
            }
        }
        #pragma unroll
        for (int m = 0; m < 8; ++m) {
            v4f h = *(const v4f*)(hs2s + c * 128 + m * 16 + quad * 4);
            #pragma unroll
            for (int r = 0; r < 4; ++r)
                rmax[m][r] = fmaxf(rmax[m][r],
                                   fmaxf(acc[m][0][r], acc[m][1][r]) + h[r]);
        }
    }

    // ---- reduce over 16 window-columns; LDS reduce; device atomicMin ----
    #pragma unroll
    for (int m = 0; m < 8; ++m) {
        #pragma unroll
        for (int r = 0; r < 4; ++r) {
            float v = rmax[m][r];
            v = fmaxf(v, __shfl_xor(v, 1, 64));
            v = fmaxf(v, __shfl_xor(v, 2, 64));
            v = fmaxf(v, __shfl_xor(v, 4, 64));
            v = fmaxf(v, __shfl_xor(v, 8, 64));
            rmax[m][r] = v;
        }
    }
    if (col == 0) {   // 4 lanes per wave (one per quad)
        #pragma unroll
        for (int m = 0; m < 8; ++m)
            #pragma unroll
            for (int r = 0; r < 4; ++r) {
                int k = m * 16 + quad * 4 + r;
                float d2 = fmaxf(-2.f * rmax[m][r], 0.f);
                atomicMin(&red[k], __float_as_uint(d2));
            }
    }
    __syncthreads();
    if (t < KK) atomicMin(&d2g[n * KK + t], red[t]);   // device-scope RMW

    // ---- last block for this n writes sqrt -> out (no threadfence) ----
    __syncthreads();   // vmcnt(0) drain: this block's d2g mins are globally done
    if (t == 0) {
        unsigned old = atomicAdd(&cnt[n], 1u);
        lastflag = (old == TILES - 1) ? 1 : 0;
    }
    __syncthreads();
    if (lastflag && t < KK) {
        // atomic RMW = coherent read of the final min at the coherence point
        unsigned bits = atomicMin(&d2g[n * KK + t], 0x7F800000u);
        out[n * KK + t] = sqrtf(__uint_as_float(bits));
    }
}

// ---------------------------------------------------------------------------
extern "C" void kernel_launch(void* const* d_in, const int* in_sizes, int n_in,
                              void* d_out, int out_size, void* d_ws, size_t ws_size,
                              hipStream_t stream) {
    const float* x   = (const float*)d_in[0];   // (N, C, L) fp32
    const float* shp = (const float*)d_in[1];   // (C, K, S) fp32
    unsigned* d2g  = (unsigned*)d_ws;
    unsigned* cnt  = (unsigned*)((char*)d_ws + WS_CNT_OFF);
    float*    hs2g = (float*)((char*)d_ws + WS_HS2_OFF);
    uint4*    shb  = (uint4*)((char*)d_ws + WS_SHB_OFF);
    float* out = (float*)d_out;

    hipLaunchKernelGGL(me_prep, dim3(32), dim3(256), 0, stream, shp, d2g, cnt, hs2g, shb);
    hipLaunchKernelGGL(me_main, dim3(NN * TILES), dim3(256), 0, stream,
                       x, (const ushort*)shb, hs2g, d2g, cnt, out);
}

// Round 5
// 80.500 us; speedup vs baseline: 2.5303x; 1.3242x over previous
//
#include <hip/hip_runtime.h>
#include <hip/hip_bf16.h>

#define NN 64
#define CC 3
#define LL 4096
#define SS 64
#define KK 128
#define WW 4033           // LL - SS + 1
#define TILES 32          // 32 window-tiles of 128 per n
#define TPB 4             // tiles per block
#define BLKN (TILES/TPB)  // 8 blocks per n

typedef __attribute__((ext_vector_type(8))) short v8s;   // 8 bf16 MFMA A/B frag
typedef __attribute__((ext_vector_type(4))) float v4f;   // 4 fp32 MFMA C/D frag

// ---- ws layout (bytes) ----
// d2g:  u32[NN*KK]        @ 0       (32768)
// cnt:  u32[NN]           @ 32768   (256)
// hs2g: f32[CC*KK]        @ 33024   (1536)  -0.5*||s||^2
// shb:  uint4[CC*1024]    @ 34560   (49152) fragment-order bf16 shapelets
#define WS_CNT_OFF 32768
#define WS_HS2_OFF 33024
#define WS_SHB_OFF 34560

__device__ __forceinline__ unsigned bf16_rne(float f) {
    unsigned u = __float_as_uint(f);
    return (u + 0x7FFFu + ((u >> 16) & 1u)) >> 16;
}

// ---------------------------------------------------------------------------
// Prep: init d2g=+inf, cnt=0, hs2, frag-order bf16 pack (B-operand order:
// chunk ((c*8+nt)*2+sc)*64+lane holds shp[c][nt*16+(lane&15)][sc*32+(lane>>4)*8+j]).
__global__ void me_prep(const float* __restrict__ shp,
                        unsigned* __restrict__ d2g,
                        unsigned* __restrict__ cnt,
                        float* __restrict__ hs2g,
                        uint4* __restrict__ shb) {
    int tid = blockIdx.x * 256 + threadIdx.x;
    if (tid < NN * KK) d2g[tid] = 0x7F800000u;     // +inf bits
    if (tid < NN) cnt[tid] = 0u;
    if (tid < CC * KK) {
        const float* r = shp + tid * SS;
        float a = 0.f;
        #pragma unroll 8
        for (int s = 0; s < SS; ++s) a += r[s] * r[s];
        hs2g[tid] = -0.5f * a;
    }
    if (tid < CC * 1024) {
        int c  = tid >> 10;
        int r  = tid & 1023;
        int nt = r >> 7;
        int sc = (r >> 6) & 1;
        int l  = r & 63;
        int row  = nt * 16 + (l & 15);
        int koff = sc * 32 + (l >> 4) * 8;
        const float* s = shp + ((size_t)(c * KK + row)) * SS + koff;
        float4 f0 = *(const float4*)s;
        float4 f1 = *(const float4*)(s + 4);
        uint4 o;
        o.x = (bf16_rne(f0.y) << 16) | bf16_rne(f0.x);
        o.y = (bf16_rne(f0.w) << 16) | bf16_rne(f0.z);
        o.z = (bf16_rne(f1.y) << 16) | bf16_rne(f1.x);
        o.w = (bf16_rne(f1.w) << 16) | bf16_rne(f1.z);
        shb[tid] = o;
    }
}

// ---------------------------------------------------------------------------
// Main: 512 blocks = (n, tile-group of 4 consecutive 128-window tiles).
// Orientation: A = x windows (M), B = shapelets (N). Per wave: 32 windows
// (2 m-tiles) x 128 shapelets (8 n-tiles) x K=64 (2 chunks).
// acc init = -0.5*x2[w] - 0.5*s2[k] (both from regs); D = -0.5*d2.
// Double-buffered x staging -> ONE barrier per tile.
__global__ __launch_bounds__(256, 2) void me_main(
        const float* __restrict__ x,
        const ushort* __restrict__ shb_g,
        const float* __restrict__ hs2g,
        unsigned* __restrict__ d2g,
        unsigned* __restrict__ cnt,
        float* __restrict__ out) {

    __shared__ __align__(16) ushort shb[CC * 8192];   // 48 KB shapelet frags
    __shared__ ushort xs2[2][2][CC][200];             // [buf][copy][c][elem] bf16
    __shared__ __align__(16) float hx2s[2][CC][128];  // [buf] -0.5*x2 (or -1e30)
    __shared__ unsigned red[KK];
    __shared__ int lastflag;

    const int b    = blockIdx.x;
    const int n    = b >> 3;          // BLKN=8 blocks per n
    const int tg   = b & 7;
    const int t    = threadIdx.x;
    const int lane = t & 63, wave = t >> 6;
    const int quad = lane >> 4, col = lane & 15;
    const int wbase = wave * 32;      // wave's window base within the tile

    if (t < KK) red[t] = 0x7F800000u;

    // ---- DMA all shapelet frags global(ws) -> LDS, once per block ----
    {
        typedef __attribute__((address_space(1))) const uint4 gu4;
        typedef __attribute__((address_space(3))) uint4 lu4;
        const uint4* gbase = (const uint4*)shb_g;
        #pragma unroll
        for (int it = 0; it < 12; ++it) {
            const uint4* gp = gbase + it * 256 + t;                 // per-lane
            uint4* lp = (uint4*)shb + (it * 256 + wave * 64);       // wave-uniform
            __builtin_amdgcn_global_load_lds((gu4*)gp, (lu4*)lp, 16, 0, 0);
        }
    }

    // ---- -0.5*s2 into registers: hsv[c][nt] (indexed by this lane's col) ----
    float hsv[CC][8];
    #pragma unroll
    for (int c = 0; c < CC; ++c)
        #pragma unroll
        for (int nt = 0; nt < 8; ++nt)
            hsv[c][nt] = hs2g[c * KK + nt * 16 + col];

    const float* xb = x + (size_t)n * (CC * LL);

    float rmax[8];
    #pragma unroll
    for (int nt = 0; nt < 8; ++nt) rmax[nt] = -3.4e38f;

    for (int j = 0; j < TPB; ++j) {
        const int buf = j & 1;
        const int w0  = (tg * TPB + j) * 128;

        // ---- one wave per channel: stage x bf16 (2 copies) + prefix scan ----
        if (wave < 3) {
            const float* xc = xb + wave * LL;
            float P0, P1, P2;
            float carry = 0.f;
            #pragma unroll
            for (int seg = 0; seg < 3; ++seg) {
                int idx = seg * 64 + lane;
                int gi  = w0 + idx;
                float v = (gi < LL) ? xc[gi] : 0.f;
                ushort hv = (ushort)bf16_rne(v);
                xs2[buf][0][wave][idx] = hv;
                if (idx > 0) xs2[buf][1][wave][idx - 1] = hv;
                float sq = v * v;
                #pragma unroll
                for (int d = 1; d < 64; d <<= 1) {
                    float u = __shfl_up(sq, d, 64);
                    if (lane >= d) sq += u;
                }
                sq += carry;
                if (seg == 0) P0 = sq; else if (seg == 1) P1 = sq; else P2 = sq;
                carry = __shfl(sq, 63, 64);
            }
            // window w: x2 = P[w+63] - P[w-1]
            float p0u = __shfl_up(P0, 1, 64);
            float p1u = __shfl_up(P1, 1, 64);
            float p2u = __shfl_up(P2, 1, 64);
            float P0e = __shfl(P0, 63, 64);
            float P1e = __shfl(P1, 63, 64);
            float I1a = (lane == 0) ? P0e : p1u;
            float I0a = (lane == 0) ? 0.f : p0u;
            float I1b = (lane == 0) ? P1e : p2u;
            hx2s[buf][wave][lane]      = (w0 + lane < WW)      ? (-0.5f * (I1a - I0a)) : -1e30f;
            hx2s[buf][wave][64 + lane] = (w0 + 64 + lane < WW) ? (-0.5f * (I1b - I1a)) : -1e30f;
        }
        __syncthreads();   // the ONLY barrier per tile (covers DMA on j==0)

        // ---- MFMA phase ----
        #pragma unroll
        for (int c = 0; c < CC; ++c) {
            // -0.5*x2 for this wave's rows: v4f broadcast reads
            v4f hxv[2];
            #pragma unroll
            for (int mt = 0; mt < 2; ++mt)
                hxv[mt] = *(const v4f*)(&hx2s[buf][c][wbase + mt * 16 + quad * 4]);
            // A-frags: 8 consecutive bf16 via dual-copy (dword-aligned) reads
            v8s af[2][2];
            #pragma unroll
            for (int mt = 0; mt < 2; ++mt)
                #pragma unroll
                for (int sc = 0; sc < 2; ++sc) {
                    int e0 = wbase + mt * 16 + col + sc * 32 + quad * 8;
                    int p  = col & 1;
                    const uint* ap = (const uint*)&xs2[buf][p][c][e0 - p];
                    union { v8s v; uint u[4]; } au;
                    au.u[0] = ap[0]; au.u[1] = ap[1];
                    au.u[2] = ap[2]; au.u[3] = ap[3];
                    af[mt][sc] = au.v;
                }
            // acc init = hx(row) + hs(col)
            v4f acc[8][2];
            #pragma unroll
            for (int nt = 0; nt < 8; ++nt) {
                float h = hsv[c][nt];
                #pragma unroll
                for (int mt = 0; mt < 2; ++mt) {
                    v4f a;
                    a[0] = hxv[mt][0] + h; a[1] = hxv[mt][1] + h;
                    a[2] = hxv[mt][2] + h; a[3] = hxv[mt][3] + h;
                    acc[nt][mt] = a;
                }
            }
            // 32 MFMA: D = A(x) * B(shp) + acc
            #pragma unroll
            for (int sc = 0; sc < 2; ++sc)
                #pragma unroll
                for (int nt = 0; nt < 8; ++nt) {
                    v8s bfr = *(const v8s*)(shb + (((c * 8 + nt) * 2 + sc) * 64 + lane) * 8);
                    acc[nt][0] = __builtin_amdgcn_mfma_f32_16x16x32_bf16(af[0][sc], bfr, acc[nt][0], 0, 0, 0);
                    acc[nt][1] = __builtin_amdgcn_mfma_f32_16x16x32_bf16(af[1][sc], bfr, acc[nt][1], 0, 0, 0);
                }
            // epilogue: max over this wave's 8 window-rows (2 mt x 4 regs)
            #pragma unroll
            for (int nt = 0; nt < 8; ++nt) {
                v4f a0 = acc[nt][0], a1 = acc[nt][1];
                float m = fmaxf(fmaxf(fmaxf(a0[0], a0[1]), fmaxf(a0[2], a0[3])),
                                fmaxf(fmaxf(a1[0], a1[1]), fmaxf(a1[2], a1[3])));
                rmax[nt] = fmaxf(rmax[nt], m);
            }
        }
        // no trailing barrier: next tile writes the OTHER buffer, and the
        // next barrier precedes any read of it (safe w/ double buffer)
    }

    // ---- reduce over quads (rows 0..15 live across quad) ----
    #pragma unroll
    for (int nt = 0; nt < 8; ++nt) {
        float v = rmax[nt];
        v = fmaxf(v, __shfl_xor(v, 16, 64));
        v = fmaxf(v, __shfl_xor(v, 32, 64));
        rmax[nt] = v;
    }
    if (quad == 0) {
        #pragma unroll
        for (int nt = 0; nt < 8; ++nt) {
            float d2 = fmaxf(-2.f * rmax[nt], 0.f);
            atomicMin(&red[nt * 16 + col], __float_as_uint(d2));
        }
    }
    __syncthreads();
    if (t < KK) atomicMin(&d2g[n * KK + t], red[t]);   // device-scope RMW

    // ---- last block for this n writes sqrt -> out ----
    __syncthreads();   // vmcnt(0) drain: d2g mins globally done before cnt
    if (t == 0) {
        unsigned old = atomicAdd(&cnt[n], 1u);
        lastflag = (old == BLKN - 1) ? 1 : 0;
    }
    __syncthreads();
    if (lastflag && t < KK) {
        unsigned bits = atomicMin(&d2g[n * KK + t], 0x7F800000u);
        out[n * KK + t] = sqrtf(__uint_as_float(bits));
    }
}

// ---------------------------------------------------------------------------
extern "C" void kernel_launch(void* const* d_in, const int* in_sizes, int n_in,
                              void* d_out, int out_size, void* d_ws, size_t ws_size,
                              hipStream_t stream) {
    const float* x   = (const float*)d_in[0];   // (N, C, L) fp32
    const float* shp = (const float*)d_in[1];   // (C, K, S) fp32
    unsigned* d2g  = (unsigned*)d_ws;
    unsigned* cnt  = (unsigned*)((char*)d_ws + WS_CNT_OFF);
    float*    hs2g = (float*)((char*)d_ws + WS_HS2_OFF);
    uint4*    shb  = (uint4*)((char*)d_ws + WS_SHB_OFF);
    float* out = (float*)d_out;

    hipLaunchKernelGGL(me_prep, dim3(32), dim3(256), 0, stream, shp, d2g, cnt, hs2g, shb);
    hipLaunchKernelGGL(me_main, dim3(NN * TILES / TPB), dim3(256), 0, stream,
                       x, (const ushort*)shb, hs2g, d2g, cnt, out);
}

// Round 6
// 79.397 us; speedup vs baseline: 2.5655x; 1.0139x over previous
//
#include <hip/hip_runtime.h>
#include <hip/hip_bf16.h>

#define NN 64
#define CC 3
#define LL 4096
#define SS 64
#define KK 128
#define WW 4033           // LL - SS + 1
#define TILES 32          // 32 window-tiles of 128 per n
#define TPB 4             // tiles per block
#define BLKN (TILES/TPB)  // 8 blocks per n

typedef __attribute__((ext_vector_type(8))) short v8s;   // 8 bf16 MFMA A/B frag
typedef __attribute__((ext_vector_type(4))) float v4f;   // 4 fp32 MFMA C/D frag

// ---- ws layout (bytes) ----
// d2g:  u32[NN*KK]        @ 0       (32768)
// cnt:  u32[NN]           @ 32768   (256)
// hs2g: f32[CC*KK]        @ 33024   (1536)   -0.5*||s||^2
// shb:  uint4[CC*1024]    @ 34560   (49152)  fragment-order bf16 shapelets
// hx2g: f32[NN*CC*4096]   @ 131072  (3.1 MB) -0.5*sliding||x_w||^2 (-1e30 pad)
#define WS_CNT_OFF 32768
#define WS_HS2_OFF 33024
#define WS_SHB_OFF 34560
#define WS_HX2_OFF 131072

__device__ __forceinline__ unsigned bf16_rne(float f) {
    unsigned u = __float_as_uint(f);
    return (u + 0x7FFFu + ((u >> 16) & 1u)) >> 16;
}

// ---------------------------------------------------------------------------
// Prep, grid 224: blocks 0..191 build the -0.5*x2 sliding table for one (n,c)
// via a block prefix-scan; blocks 192..223 do init/hs2/frag-pack (as before).
__global__ __launch_bounds__(256) void me_prep(
        const float* __restrict__ x,
        const float* __restrict__ shp,
        unsigned* __restrict__ d2g,
        unsigned* __restrict__ cnt,
        float* __restrict__ hs2g,
        uint4* __restrict__ shb,
        float* __restrict__ hx2g) {
    const int b = blockIdx.x, t = threadIdx.x;
    if (b < NN * CC) {
        const int n = b / 3, c = b - n * 3;
        __shared__ float P[LL];      // inclusive prefix of x^2
        __shared__ float wtot[4];
        const int lane = t & 63, wave = t >> 6;
        const float* xc = x + ((size_t)n * CC + c) * LL;
        const int base = t * 16;
        float q[16];
        {
            float4 A0 = *(const float4*)(xc + base);
            float4 A1 = *(const float4*)(xc + base + 4);
            float4 A2 = *(const float4*)(xc + base + 8);
            float4 A3 = *(const float4*)(xc + base + 12);
            q[0]=A0.x; q[1]=A0.y; q[2]=A0.z;  q[3]=A0.w;
            q[4]=A1.x; q[5]=A1.y; q[6]=A1.z;  q[7]=A1.w;
            q[8]=A2.x; q[9]=A2.y; q[10]=A2.z; q[11]=A2.w;
            q[12]=A3.x;q[13]=A3.y;q[14]=A3.z; q[15]=A3.w;
        }
        float run = 0.f;
        #pragma unroll
        for (int i = 0; i < 16; ++i) { run += q[i] * q[i]; q[i] = run; }
        // wave-inclusive scan of per-thread totals
        float sc = run;
        #pragma unroll
        for (int d = 1; d < 64; d <<= 1) {
            float u = __shfl_up(sc, d, 64);
            if (lane >= d) sc += u;
        }
        if (lane == 63) wtot[wave] = sc;
        __syncthreads();
        float excl = sc - run;
        for (int w2 = 0; w2 < wave; ++w2) excl += wtot[w2];
        #pragma unroll
        for (int i = 0; i < 16; ++i) q[i] += excl;
        *(float4*)(P + base)      = make_float4(q[0], q[1], q[2], q[3]);
        *(float4*)(P + base + 4)  = make_float4(q[4], q[5], q[6], q[7]);
        *(float4*)(P + base + 8)  = make_float4(q[8], q[9], q[10], q[11]);
        *(float4*)(P + base + 12) = make_float4(q[12], q[13], q[14], q[15]);
        __syncthreads();
        float* dst = hx2g + ((size_t)n * CC + c) * LL;
        #pragma unroll
        for (int i = 0; i < 16; ++i) {
            int w = base + i;
            float o = -1e30f;                      // pad: windows >= WW masked
            if (w < WW) {
                float I1 = P[w + 63];
                float I0 = (w > 0) ? P[w - 1] : 0.f;
                o = -0.5f * (I1 - I0);
            }
            dst[w] = o;
        }
    } else {
        int tid = (b - NN * CC) * 256 + t;
        if (tid < NN * KK) d2g[tid] = 0x7F800000u;     // +inf bits
        if (tid < NN) cnt[tid] = 0u;
        if (tid < CC * KK) {
            const float* r = shp + tid * SS;
            float a = 0.f;
            #pragma unroll 8
            for (int s = 0; s < SS; ++s) a += r[s] * r[s];
            hs2g[tid] = -0.5f * a;
        }
        if (tid < CC * 1024) {
            // B-operand frag order: chunk ((c*8+nt)*2+sc)*64+lane holds
            // shp[c][nt*16+(lane&15)][sc*32+(lane>>4)*8 + j], j=0..7 (RNE bf16)
            int c  = tid >> 10;
            int r  = tid & 1023;
            int nt = r >> 7;
            int scb = (r >> 6) & 1;
            int l  = r & 63;
            int row  = nt * 16 + (l & 15);
            int koff = scb * 32 + (l >> 4) * 8;
            const float* s = shp + ((size_t)(c * KK + row)) * SS + koff;
            float4 f0 = *(const float4*)s;
            float4 f1 = *(const float4*)(s + 4);
            uint4 o;
            o.x = (bf16_rne(f0.y) << 16) | bf16_rne(f0.x);
            o.y = (bf16_rne(f0.w) << 16) | bf16_rne(f0.z);
            o.z = (bf16_rne(f1.y) << 16) | bf16_rne(f1.x);
            o.w = (bf16_rne(f1.w) << 16) | bf16_rne(f1.z);
            shb[tid] = o;
        }
    }
}

// ---------------------------------------------------------------------------
// Main: 512 blocks = (n, group of 4 consecutive 128-window tiles).
// A = x windows (M), B = shapelets (N); wave = 32 windows x 128 shapelets.
// Per tile: cheap bf16 dual-copy staging -> ONE barrier -> MFMA phase.
// acc init = -0.5*s2 (regs); epilogue adds precomputed -0.5*x2 from global
// (pad rows already -1e30 -> masking free). min d2 = max(-2*maxD, 0).
__global__ __launch_bounds__(256, 2) void me_main(
        const float* __restrict__ x,
        const ushort* __restrict__ shb_g,
        const float* __restrict__ hs2g,
        const float* __restrict__ hx2g,
        unsigned* __restrict__ d2g,
        unsigned* __restrict__ cnt,
        float* __restrict__ out) {

    __shared__ __align__(16) ushort shb[CC * 8192];   // 48 KB shapelet frags
    __shared__ ushort xs2[2][2][CC][200];             // [buf][copy][c][elem] bf16
    __shared__ unsigned red[KK];
    __shared__ int lastflag;

    const int b    = blockIdx.x;
    const int n    = b >> 3;          // BLKN=8 blocks per n
    const int tg   = b & 7;
    const int t    = threadIdx.x;
    const int lane = t & 63, wave = t >> 6;
    const int quad = lane >> 4, col = lane & 15;
    const int wbase = wave * 32;

    if (t < KK) red[t] = 0x7F800000u;

    // ---- DMA all shapelet frags global(ws) -> LDS, once per block ----
    {
        typedef __attribute__((address_space(1))) const uint4 gu4;
        typedef __attribute__((address_space(3))) uint4 lu4;
        const uint4* gbase = (const uint4*)shb_g;
        #pragma unroll
        for (int it = 0; it < 12; ++it) {
            const uint4* gp = gbase + it * 256 + t;                 // per-lane
            uint4* lp = (uint4*)shb + (it * 256 + wave * 64);       // wave-uniform
            __builtin_amdgcn_global_load_lds((gu4*)gp, (lu4*)lp, 16, 0, 0);
        }
    }

    // ---- -0.5*s2 into registers (indexed by this lane's col) ----
    float hsv[CC][8];
    #pragma unroll
    for (int c = 0; c < CC; ++c)
        #pragma unroll
        for (int nt = 0; nt < 8; ++nt)
            hsv[c][nt] = hs2g[c * KK + nt * 16 + col];

    const float* xb   = x + (size_t)n * (CC * LL);
    const float* hx2b = hx2g + (size_t)n * (CC * LL);

    float rmax[8];
    #pragma unroll
    for (int nt = 0; nt < 8; ++nt) rmax[nt] = -3.4e38f;

    for (int j = 0; j < TPB; ++j) {
        const int buf = j & 1;
        const int w0  = (tg * TPB + j) * 128;

        // ---- stage x bf16, two copies (copy1 shifted by 1 elem) ----
        #pragma unroll
        for (int it = 0; it < 3; ++it) {
            int e = t + it * 256;
            if (e < 576) {
                int c = e / 192, idx = e - c * 192;
                int gi = w0 + idx;
                float vx = (gi < LL) ? xb[c * LL + gi] : 0.f;
                ushort hv = (ushort)bf16_rne(vx);
                xs2[buf][0][c][idx] = hv;
                if (idx > 0) xs2[buf][1][c][idx - 1] = hv;
            }
        }
        __syncthreads();   // the ONLY barrier per tile (covers DMA on j==0)

        // ---- MFMA phase ----
        #pragma unroll
        for (int c = 0; c < CC; ++c) {
            // -0.5*x2 for this wave's rows: global v4f (L2-resident table)
            const float* hp = hx2b + c * LL + w0 + wbase + quad * 4;
            v4f hxv0 = *(const v4f*)(hp);
            v4f hxv1 = *(const v4f*)(hp + 16);
            // A-frags: 8 consecutive bf16 via dual-copy (dword-aligned) reads
            v8s af[2][2];
            #pragma unroll
            for (int mt = 0; mt < 2; ++mt)
                #pragma unroll
                for (int sc = 0; sc < 2; ++sc) {
                    int e0 = wbase + mt * 16 + col + sc * 32 + quad * 8;
                    int p  = col & 1;
                    const uint* ap = (const uint*)&xs2[buf][p][c][e0 - p];
                    union { v8s v; uint u[4]; } au;
                    au.u[0] = ap[0]; au.u[1] = ap[1];
                    au.u[2] = ap[2]; au.u[3] = ap[3];
                    af[mt][sc] = au.v;
                }
            // acc init = -0.5*s2 (col-dependent only)
            v4f acc[8][2];
            #pragma unroll
            for (int nt = 0; nt < 8; ++nt) {
                float h = hsv[c][nt];
                v4f a = {h, h, h, h};
                acc[nt][0] = a; acc[nt][1] = a;
            }
            // 32 MFMA: D = A(x) * B(shp) + acc
            #pragma unroll
            for (int sc = 0; sc < 2; ++sc)
                #pragma unroll
                for (int nt = 0; nt < 8; ++nt) {
                    v8s bfr = *(const v8s*)(shb + (((c * 8 + nt) * 2 + sc) * 64 + lane) * 8);
                    acc[nt][0] = __builtin_amdgcn_mfma_f32_16x16x32_bf16(af[0][sc], bfr, acc[nt][0], 0, 0, 0);
                    acc[nt][1] = __builtin_amdgcn_mfma_f32_16x16x32_bf16(af[1][sc], bfr, acc[nt][1], 0, 0, 0);
                }
            // epilogue: add -0.5*x2 (rows; -1e30 pads mask invalid windows)
            #pragma unroll
            for (int nt = 0; nt < 8; ++nt) {
                v4f a0 = acc[nt][0], a1 = acc[nt][1];
                float m = -3.4e38f;
                #pragma unroll
                for (int r = 0; r < 4; ++r)
                    m = fmaxf(m, fmaxf(a0[r] + hxv0[r], a1[r] + hxv1[r]));
                rmax[nt] = fmaxf(rmax[nt], m);
            }
        }
        // no trailing barrier: next tile writes the OTHER buffer
    }

    // ---- reduce over quads (window rows live across quad+regs) ----
    #pragma unroll
    for (int nt = 0; nt < 8; ++nt) {
        float v = rmax[nt];
        v = fmaxf(v, __shfl_xor(v, 16, 64));
        v = fmaxf(v, __shfl_xor(v, 32, 64));
        rmax[nt] = v;
    }
    if (quad == 0) {
        #pragma unroll
        for (int nt = 0; nt < 8; ++nt) {
            float d2 = fmaxf(-2.f * rmax[nt], 0.f);
            atomicMin(&red[nt * 16 + col], __float_as_uint(d2));
        }
    }
    __syncthreads();
    if (t < KK) atomicMin(&d2g[n * KK + t], red[t]);   // device-scope RMW

    // ---- last block for this n writes sqrt -> out ----
    __syncthreads();   // vmcnt(0) drain: d2g mins globally done before cnt
    if (t == 0) {
        unsigned old = atomicAdd(&cnt[n], 1u);
        lastflag = (old == BLKN - 1) ? 1 : 0;
    }
    __syncthreads();
    if (lastflag && t < KK) {
        unsigned bits = atomicMin(&d2g[n * KK + t], 0x7F800000u);
        out[n * KK + t] = sqrtf(__uint_as_float(bits));
    }
}

// ---------------------------------------------------------------------------
extern "C" void kernel_launch(void* const* d_in, const int* in_sizes, int n_in,
                              void* d_out, int out_size, void* d_ws, size_t ws_size,
                              hipStream_t stream) {
    const float* x   = (const float*)d_in[0];   // (N, C, L) fp32
    const float* shp = (const float*)d_in[1];   // (C, K, S) fp32
    unsigned* d2g  = (unsigned*)d_ws;
    unsigned* cnt  = (unsigned*)((char*)d_ws + WS_CNT_OFF);
    float*    hs2g = (float*)((char*)d_ws + WS_HS2_OFF);
    uint4*    shb  = (uint4*)((char*)d_ws + WS_SHB_OFF);
    float*    hx2g = (float*)((char*)d_ws + WS_HX2_OFF);
    float* out = (float*)d_out;

    hipLaunchKernelGGL(me_prep, dim3(NN * CC + 32), dim3(256), 0, stream,
                       x, shp, d2g, cnt, hs2g, shb, hx2g);
    hipLaunchKernelGGL(me_main, dim3(NN * TILES / TPB), dim3(256), 0, stream,
                       x, (const ushort*)shb, hs2g, hx2g, d2g, cnt, out);
}

// Round 7
// 76.374 us; speedup vs baseline: 2.6670x; 1.0396x over previous
//
#include <hip/hip_runtime.h>
#include <hip/hip_bf16.h>

#define NN 64
#define CC 3
#define LL 4096
#define SS 64
#define KK 128
#define WW 4033           // LL - SS + 1
#define BLKN 8            // blocks per n (each covers 512 windows)

typedef __attribute__((ext_vector_type(8))) short v8s;   // 8 bf16 MFMA A/B frag
typedef __attribute__((ext_vector_type(4))) float v4f;   // 4 fp32 MFMA C/D frag

// ---- ws layout (bytes) ----
// d2g:  u32[NN*KK]        @ 0       (32768)
// cnt:  u32[NN]           @ 32768   (256)
// hs2g: f32[CC*KK]        @ 33024   (1536)   -0.5*||s||^2
// shb:  uint4[CC*1024]    @ 34560   (49152)  fragment-order bf16 shapelets
// hx2g: f32[NN*CC*4096]   @ 131072  (3.1 MB) -0.5*sliding||x_w||^2 (-1e30 pad)
#define WS_CNT_OFF 32768
#define WS_HS2_OFF 33024
#define WS_SHB_OFF 34560
#define WS_HX2_OFF 131072

__device__ __forceinline__ unsigned bf16_rne(float f) {
    unsigned u = __float_as_uint(f);
    return (u + 0x7FFFu + ((u >> 16) & 1u)) >> 16;
}

// ---------------------------------------------------------------------------
// Prep, grid 224: blocks 0..191 build the -0.5*x2 sliding table for one (n,c)
// via a block prefix-scan; blocks 192..223 do init/hs2/frag-pack.
__global__ __launch_bounds__(256) void me_prep(
        const float* __restrict__ x,
        const float* __restrict__ shp,
        unsigned* __restrict__ d2g,
        unsigned* __restrict__ cnt,
        float* __restrict__ hs2g,
        uint4* __restrict__ shb,
        float* __restrict__ hx2g) {
    const int b = blockIdx.x, t = threadIdx.x;
    if (b < NN * CC) {
        const int n = b / 3, c = b - n * 3;
        __shared__ float P[LL];      // inclusive prefix of x^2
        __shared__ float wtot[4];
        const int lane = t & 63, wave = t >> 6;
        const float* xc = x + ((size_t)n * CC + c) * LL;
        const int base = t * 16;
        float q[16];
        {
            float4 A0 = *(const float4*)(xc + base);
            float4 A1 = *(const float4*)(xc + base + 4);
            float4 A2 = *(const float4*)(xc + base + 8);
            float4 A3 = *(const float4*)(xc + base + 12);
            q[0]=A0.x; q[1]=A0.y; q[2]=A0.z;  q[3]=A0.w;
            q[4]=A1.x; q[5]=A1.y; q[6]=A1.z;  q[7]=A1.w;
            q[8]=A2.x; q[9]=A2.y; q[10]=A2.z; q[11]=A2.w;
            q[12]=A3.x;q[13]=A3.y;q[14]=A3.z; q[15]=A3.w;
        }
        float run = 0.f;
        #pragma unroll
        for (int i = 0; i < 16; ++i) { run += q[i] * q[i]; q[i] = run; }
        float sc = run;
        #pragma unroll
        for (int d = 1; d < 64; d <<= 1) {
            float u = __shfl_up(sc, d, 64);
            if (lane >= d) sc += u;
        }
        if (lane == 63) wtot[wave] = sc;
        __syncthreads();
        float excl = sc - run;
        for (int w2 = 0; w2 < wave; ++w2) excl += wtot[w2];
        #pragma unroll
        for (int i = 0; i < 16; ++i) q[i] += excl;
        *(float4*)(P + base)      = make_float4(q[0], q[1], q[2], q[3]);
        *(float4*)(P + base + 4)  = make_float4(q[4], q[5], q[6], q[7]);
        *(float4*)(P + base + 8)  = make_float4(q[8], q[9], q[10], q[11]);
        *(float4*)(P + base + 12) = make_float4(q[12], q[13], q[14], q[15]);
        __syncthreads();
        float* dst = hx2g + ((size_t)n * CC + c) * LL;
        #pragma unroll
        for (int i = 0; i < 16; ++i) {
            int w = base + i;
            float o = -1e30f;                      // pad: windows >= WW masked
            if (w < WW) {
                float I1 = P[w + 63];
                float I0 = (w > 0) ? P[w - 1] : 0.f;
                o = -0.5f * (I1 - I0);
            }
            dst[w] = o;
        }
    } else {
        int tid = (b - NN * CC) * 256 + t;
        if (tid < NN * KK) d2g[tid] = 0x7F800000u;     // +inf bits
        if (tid < NN) cnt[tid] = 0u;
        if (tid < CC * KK) {
            const float* r = shp + tid * SS;
            float a = 0.f;
            #pragma unroll 8
            for (int s = 0; s < SS; ++s) a += r[s] * r[s];
            hs2g[tid] = -0.5f * a;
        }
        if (tid < CC * 1024) {
            // B-operand frag order: chunk ((c*8+nt)*2+sc)*64+lane holds
            // shp[c][nt*16+(lane&15)][sc*32+(lane>>4)*8 + j], j=0..7 (RNE bf16)
            int c   = tid >> 10;
            int r   = tid & 1023;
            int nt  = r >> 7;
            int scb = (r >> 6) & 1;
            int l   = r & 63;
            int row  = nt * 16 + (l & 15);
            int koff = scb * 32 + (l >> 4) * 8;
            const float* s = shp + ((size_t)(c * KK + row)) * SS + koff;
            float4 f0 = *(const float4*)s;
            float4 f1 = *(const float4*)(s + 4);
            uint4 o;
            o.x = (bf16_rne(f0.y) << 16) | bf16_rne(f0.x);
            o.y = (bf16_rne(f0.w) << 16) | bf16_rne(f0.z);
            o.z = (bf16_rne(f1.y) << 16) | bf16_rne(f1.x);
            o.w = (bf16_rne(f1.w) << 16) | bf16_rne(f1.z);
            shb[tid] = o;
        }
    }
}

// ---------------------------------------------------------------------------
// Main: 512 blocks = (n, 512-window group). Per iteration: 256-window
// supertile; wave = 64 windows (4 m-tiles) x 128 shapelets. B-frags reused
// across 4 m-tiles -> LDS B-traffic halved vs 32-window waves.
// acc init = -0.5*s2 (regs); epilogue adds precomputed -0.5*x2 (global,
// -1e30 pads mask invalid windows). min d2 = max(-2*maxD, 0).
__global__ __launch_bounds__(256, 2) void me_main(
        const float* __restrict__ x,
        const ushort* __restrict__ shb_g,
        const float* __restrict__ hs2g,
        const float* __restrict__ hx2g,
        unsigned* __restrict__ d2g,
        unsigned* __restrict__ cnt,
        float* __restrict__ out) {

    __shared__ __align__(16) ushort shb[CC * 8192];   // 48 KB shapelet frags
    __shared__ __align__(8) ushort xs2[2][2][CC][320];// [buf][copy][c] bf16 x
    __shared__ unsigned red[KK];
    __shared__ int lastflag;

    const int b    = blockIdx.x;
    const int n    = b >> 3;          // BLKN=8 blocks per n
    const int tg   = b & 7;
    const int t    = threadIdx.x;
    const int lane = t & 63, wave = t >> 6;
    const int quad = lane >> 4, col = lane & 15;
    const int wbase = wave * 64;      // wave's window base within supertile

    if (t < KK) red[t] = 0x7F800000u;

    // ---- DMA all shapelet frags global(ws) -> LDS, once per block ----
    {
        typedef __attribute__((address_space(1))) const uint4 gu4;
        typedef __attribute__((address_space(3))) uint4 lu4;
        const uint4* gbase = (const uint4*)shb_g;
        #pragma unroll
        for (int it = 0; it < 12; ++it) {
            const uint4* gp = gbase + it * 256 + t;                 // per-lane
            uint4* lp = (uint4*)shb + (it * 256 + wave * 64);       // wave-uniform
            __builtin_amdgcn_global_load_lds((gu4*)gp, (lu4*)lp, 16, 0, 0);
        }
    }

    // ---- -0.5*s2 into registers (indexed by this lane's col) ----
    float hsv[CC][8];
    #pragma unroll
    for (int c = 0; c < CC; ++c)
        #pragma unroll
        for (int nt = 0; nt < 8; ++nt)
            hsv[c][nt] = hs2g[c * KK + nt * 16 + col];

    const float* xb   = x + (size_t)n * (CC * LL);
    const float* hx2b = hx2g + (size_t)n * (CC * LL);

    float rmax[8];
    #pragma unroll
    for (int nt = 0; nt < 8; ++nt) rmax[nt] = -3.4e38f;

    for (int it = 0; it < 2; ++it) {
        const int buf = it;
        const int w0  = tg * 512 + it * 256;

        // ---- stage 256+63 x elems per channel, bf16 dual-copy ----
        if (t < 240) {
            int c = t / 80, q = t - c * 80;
            int idx = q * 4, gi = w0 + idx;
            float4 v;
            if (gi + 3 < LL) v = *(const float4*)(xb + c * LL + gi);
            else {
                v.x = (gi     < LL) ? xb[c * LL + gi]     : 0.f;
                v.y = (gi + 1 < LL) ? xb[c * LL + gi + 1] : 0.f;
                v.z = (gi + 2 < LL) ? xb[c * LL + gi + 2] : 0.f;
                v.w = (gi + 3 < LL) ? xb[c * LL + gi + 3] : 0.f;
            }
            unsigned h0 = bf16_rne(v.x), h1 = bf16_rne(v.y);
            unsigned h2 = bf16_rne(v.z), h3 = bf16_rne(v.w);
            uint2 p0; p0.x = h0 | (h1 << 16); p0.y = h2 | (h3 << 16);
            *(uint2*)&xs2[buf][0][c][idx] = p0;                 // copy0: x[i]
            if (idx > 0) xs2[buf][1][c][idx - 1] = (ushort)h0;  // copy1: x[i+1]
            *(uint*)&xs2[buf][1][c][idx] = h1 | (h2 << 16);
            xs2[buf][1][c][idx + 2] = (ushort)h3;
        }
        __syncthreads();   // one barrier per iteration (covers DMA on it==0)

        #pragma unroll
        for (int c = 0; c < CC; ++c) {
            // -0.5*x2 for this wave's 64 window rows (global, L2-resident)
            const float* hp = hx2b + c * LL + w0 + wbase + quad * 4;
            v4f hxv[4];
            #pragma unroll
            for (int mt = 0; mt < 4; ++mt) hxv[mt] = *(const v4f*)(hp + mt * 16);
            // A-frags: 4 m-tiles x 2 k-chunks, dual-copy dword-aligned reads
            v8s af[4][2];
            #pragma unroll
            for (int mt = 0; mt < 4; ++mt)
                #pragma unroll
                for (int sc = 0; sc < 2; ++sc) {
                    int e0 = wbase + mt * 16 + col + sc * 32 + quad * 8;
                    int p  = col & 1;
                    const uint* ap = (const uint*)&xs2[buf][p][c][e0 - p];
                    union { v8s v; uint u[4]; } au;
                    au.u[0] = ap[0]; au.u[1] = ap[1];
                    au.u[2] = ap[2]; au.u[3] = ap[3];
                    af[mt][sc] = au.v;
                }
            // two groups of 4 n-tiles to bound acc register pressure
            #pragma unroll
            for (int g = 0; g < 2; ++g) {
                v4f acc[4][4];   // [nt2][mt]
                #pragma unroll
                for (int nt2 = 0; nt2 < 4; ++nt2) {
                    float h = hsv[c][g * 4 + nt2];
                    v4f a = {h, h, h, h};
                    #pragma unroll
                    for (int mt = 0; mt < 4; ++mt) acc[nt2][mt] = a;
                }
                #pragma unroll
                for (int sc = 0; sc < 2; ++sc)
                    #pragma unroll
                    for (int nt2 = 0; nt2 < 4; ++nt2) {
                        int nt = g * 4 + nt2;
                        v8s bfr = *(const v8s*)(shb + (((c * 8 + nt) * 2 + sc) * 64 + lane) * 8);
                        #pragma unroll
                        for (int mt = 0; mt < 4; ++mt)
                            acc[nt2][mt] = __builtin_amdgcn_mfma_f32_16x16x32_bf16(
                                af[mt][sc], bfr, acc[nt2][mt], 0, 0, 0);
                    }
                // epilogue: add -0.5*x2 rows, fold max over 16 window rows
                #pragma unroll
                for (int nt2 = 0; nt2 < 4; ++nt2) {
                    float m = -3.4e38f;
                    #pragma unroll
                    for (int mt = 0; mt < 4; ++mt) {
                        v4f a = acc[nt2][mt];
                        #pragma unroll
                        for (int r = 0; r < 4; ++r)
                            m = fmaxf(m, a[r] + hxv[mt][r]);
                    }
                    rmax[g * 4 + nt2] = fmaxf(rmax[g * 4 + nt2], m);
                }
            }
        }
        // no trailing barrier: next iteration writes the other buffer
    }

    // ---- reduce over quads (window rows live across quad+regs) ----
    #pragma unroll
    for (int nt = 0; nt < 8; ++nt) {
        float v = rmax[nt];
        v = fmaxf(v, __shfl_xor(v, 16, 64));
        v = fmaxf(v, __shfl_xor(v, 32, 64));
        rmax[nt] = v;
    }
    if (quad == 0) {
        #pragma unroll
        for (int nt = 0; nt < 8; ++nt) {
            float d2 = fmaxf(-2.f * rmax[nt], 0.f);
            atomicMin(&red[nt * 16 + col], __float_as_uint(d2));
        }
    }
    __syncthreads();
    if (t < KK) atomicMin(&d2g[n * KK + t], red[t]);   // device-scope RMW

    // ---- last block for this n writes sqrt -> out ----
    __syncthreads();   // vmcnt(0) drain: d2g mins globally done before cnt
    if (t == 0) {
        unsigned old = atomicAdd(&cnt[n], 1u);
        lastflag = (old == BLKN - 1) ? 1 : 0;
    }
    __syncthreads();
    if (lastflag && t < KK) {
        unsigned bits = atomicMin(&d2g[n * KK + t], 0x7F800000u);
        out[n * KK + t] = sqrtf(__uint_as_float(bits));
    }
}

// ---------------------------------------------------------------------------
extern "C" void kernel_launch(void* const* d_in, const int* in_sizes, int n_in,
                              void* d_out, int out_size, void* d_ws, size_t ws_size,
                              hipStream_t stream) {
    const float* x   = (const float*)d_in[0];   // (N, C, L) fp32
    const float* shp = (const float*)d_in[1];   // (C, K, S) fp32
    unsigned* d2g  = (unsigned*)d_ws;
    unsigned* cnt  = (unsigned*)((char*)d_ws + WS_CNT_OFF);
    float*    hs2g = (float*)((char*)d_ws + WS_HS2_OFF);
    uint4*    shb  = (uint4*)((char*)d_ws + WS_SHB_OFF);
    float*    hx2g = (float*)((char*)d_ws + WS_HX2_OFF);
    float* out = (float*)d_out;

    hipLaunchKernelGGL(me_prep, dim3(NN * CC + 32), dim3(256), 0, stream,
                       x, shp, d2g, cnt, hs2g, shb, hx2g);
    hipLaunchKernelGGL(me_main, dim3(NN * BLKN), dim3(256), 0, stream,
                       x, (const ushort*)shb, hs2g, hx2g, d2g, cnt, out);
}